// Round 7
// baseline (25.575 us; speedup 1.0000x reference)
//
#include <hip/hip_runtime.h>

#define EPSV 1e-4f
#define LOG2E 1.4426950408889634f

typedef float v4f __attribute__((ext_vector_type(4)));

// Fast cyclic-Jacobi rotation for the symmetric 3x3, pair (p,q), other r.
// rcp/rsq approx (2^-22 rel) keep V orthonormal to ~1e-6 over 12 rotations;
// output tolerance is 8.48 absmax, current error 0.25 -> ample headroom.
// tau=+-inf (tiny apq0) -> sqrtf(inf)=inf -> rcp(inf)=0 -> t=0 safely.
__device__ __forceinline__ void jrot(float& app, float& aqq, float& apq,
                                     float& arp, float& arq,
                                     float& vap, float& vaq,
                                     float& vbp, float& vbq,
                                     float& vcp, float& vcq) {
  const float apq0 = apq;
  const float tau = (aqq - app) * (0.5f * __builtin_amdgcn_rcpf(apq0));
  float t = copysignf(
      __builtin_amdgcn_rcpf(fabsf(tau) + sqrtf(fmaf(tau, tau, 1.0f))), tau);
  if (apq0 == 0.0f) t = 0.0f;  // covers the tau=NaN case (aqq==app too)
  const float c = __builtin_amdgcn_rsqf(fmaf(t, t, 1.0f));
  const float s = t * c;
  const float d = t * apq0;
  app -= d; aqq += d; apq = 0.0f;
  float x, y;
  x = arp; y = arq; arp = fmaf(c, x, -(s * y)); arq = fmaf(s, x, c * y);
  x = vap; y = vaq; vap = fmaf(c, x, -(s * y)); vaq = fmaf(s, x, c * y);
  x = vbp; y = vbq; vbp = fmaf(c, x, -(s * y)); vbq = fmaf(s, x, c * y);
  x = vcp; y = vcq; vcp = fmaf(c, x, -(s * y)); vcq = fmaf(s, x, c * y);
}

// One wave (64 threads) per block; each thread owns TWO elements processed in
// two sequential phases. Phase B's eigen/valgen overlaps phase A's store
// drain (stores are fire-and-forget) -- breaks the all-resident lockstep that
// kept HBM idle during the compute phase in rounds 1-6. All valgen/LDS/store
// work is full-wave (no exec-masked sections). LDS 20.9KB -> 7 blocks/CU.
__global__ __launch_bounds__(64, 2) void spd_decoder_kernel(
    const float* __restrict__ vech, const float* __restrict__ W1,
    const float* __restrict__ W2, const float* __restrict__ W3,
    float* __restrict__ out, int B) {
  __shared__ float Tsh[21];                     // W2@W1 (7x3)
  __shared__ float Msh[27];                     // W3@W2@W1 (9x3)
  __shared__ __align__(16) float buf[64 * 81];  // 64-element staging, 20736 B

  const int l = threadIdx.x;  // single wave: no __syncthreads needed anywhere

  // ---- issue both elements' input loads first (latency under prologue) ----
  const int ebase = blockIdx.x * 128 + l;
  const float2* va = reinterpret_cast<const float2*>(vech + (size_t)ebase * 6);
  const float2* vb =
      reinterpret_cast<const float2*>(vech + (size_t)(ebase + 64) * 6);
  const float2 A0 = va[0], A1 = va[1], A2 = va[2];
  const float2 B0 = vb[0], B1 = vb[1], B2 = vb[2];

  // ---- per-block M = W3@W2@W1 via LDS (wave-internal: DS pipe is in-order,
  // so write->read ordering holds without a barrier; fences keep the
  // compiler honest) ----
  if (l < 21) {
    const int r = l / 3, c = l % 3;
    float acc = 0.f;
#pragma unroll
    for (int j = 0; j < 5; ++j) acc += W2[r * 5 + j] * W1[j * 3 + c];
    Tsh[l] = acc;
  }
  asm volatile("s_waitcnt lgkmcnt(0)" ::: "memory");
  if (l < 27) {
    const int r = l / 3, c = l % 3;
    float acc = 0.f;
#pragma unroll
    for (int j = 0; j < 7; ++j) acc += W3[r * 7 + j] * Tsh[j * 3 + c];
    Msh[l] = acc;
  }
  asm volatile("s_waitcnt lgkmcnt(0)" ::: "memory");

  float M[27];
#pragma unroll
  for (int i = 0; i < 27; ++i) M[i] = Msh[i];

  float* const dst = buf + l * 81;  // word stride 81: 2 lanes/bank = free
  const v4f* const rb = reinterpret_cast<const v4f*>(buf);

#pragma unroll
  for (int p = 0; p < 2; ++p) {  // fully unrolled: all indexing static
    // ---- build symmetric 3x3 for this phase's element ----
    const float2 q0 = p ? B0 : A0, q1 = p ? B1 : A1, q2 = p ? B2 : A2;
    float a00 = q0.x, a01 = q0.y, a02 = q1.x, a11 = q1.y, a12 = q2.x,
          a22 = q2.y;

    // ---- 3x3 Jacobi, 4 sweeps (12 rotations), V accumulated ----
    float v00 = 1.f, v01 = 0.f, v02 = 0.f;
    float v10 = 0.f, v11 = 1.f, v12 = 0.f;
    float v20 = 0.f, v21 = 0.f, v22 = 1.f;
#pragma unroll
    for (int sweep = 0; sweep < 4; ++sweep) {
      jrot(a00, a11, a01, a02, a12, v00, v01, v10, v11, v20, v21);  // (0,1)
      jrot(a00, a22, a02, a01, a12, v00, v02, v10, v12, v20, v22);  // (0,2)
      jrot(a11, a22, a12, a01, a02, v01, v02, v11, v12, v21, v22);  // (1,2)
    }

    const float e0 = exp2f(a00 * LOG2E) - EPSV;
    const float e1 = exp2f(a11 * LOG2E) - EPSV;
    const float e2 = exp2f(a22 * LOG2E) - EPSV;

    // ---- g_k = M v_k ----
    float g0[9], g1[9], g2[9];
#pragma unroll
    for (int i = 0; i < 9; ++i) {
      const float m0 = M[i * 3 + 0], m1 = M[i * 3 + 1], m2 = M[i * 3 + 2];
      g0[i] = fmaf(m0, v00, fmaf(m1, v10, m2 * v20));
      g1[i] = fmaf(m0, v01, fmaf(m1, v11, m2 * v21));
      g2[i] = fmaf(m0, v02, fmaf(m1, v12, m2 * v22));
    }

    // ---- full-wave valgen + staging: lane l stages its own element ----
#pragma unroll
    for (int i = 0; i < 9; ++i) {
      const float t0 = e0 * g0[i], t1 = e1 * g1[i], t2 = e2 * g2[i];
#pragma unroll
      for (int j = 0; j < 9; ++j) {
        float val = fmaf(t0, g0[j], fmaf(t1, g1[j], t2 * g2[j]));
        if (i == j) val += EPSV;  // compile-time after unroll
        dst[i * 9 + j] = val;
      }
    }
    // cross-lane RAW: this wave's writes land before its reads (in-order DS)
    asm volatile("s_waitcnt lgkmcnt(0)" ::: "memory");

    // ---- full-wave coalesced nt-store: 5184 floats = 1296 float4 ----
    const size_t fb = (size_t)(blockIdx.x * 128 + p * 64) * 81;  // 16B-aligned
    v4f* op = reinterpret_cast<v4f*>(out + fb);
#pragma unroll
    for (int it = 0; it < 20; ++it)
      __builtin_nontemporal_store(rb[it * 64 + l], op + it * 64 + l);
    if (l < 16) __builtin_nontemporal_store(rb[1280 + l], op + 1280 + l);
    // (no fence after reads: per-wave DS in-order covers WAR into phase B)
  }
}

extern "C" void kernel_launch(void* const* d_in, const int* in_sizes, int n_in,
                              void* d_out, int out_size, void* d_ws, size_t ws_size,
                              hipStream_t stream) {
  const float* vech = (const float*)d_in[0];
  const float* W1 = (const float*)d_in[1];
  const float* W2 = (const float*)d_in[2];
  const float* W3 = (const float*)d_in[3];
  float* out = (float*)d_out;
  const int B = in_sizes[0] / 6;  // 262144
  dim3 grid(B / 128), block(64);
  hipLaunchKernelGGL(spd_decoder_kernel, grid, block, 0, stream,
                     vech, W1, W2, W3, out, B);
}

// Round 8
// 24.646 us; speedup vs baseline: 1.0377x; 1.0377x over previous
//
#include <hip/hip_runtime.h>

#define EPSV 1e-4f
#define LOG2E 1.4426950408889634f

typedef float v4f __attribute__((ext_vector_type(4)));

// Fast cyclic-Jacobi rotation for the symmetric 3x3, pair (p,q), other r.
// v_rcp/v_rsq (1ulp-ish, 2^-22 rel) replace IEEE divides: cuts ~32 cycles of
// dependency chain per rotation. V stays orthonormal to ~1e-6 over 12
// rotations; tolerance is 8.48 absmax vs current 0.25 -> ample headroom.
// tau=+-inf (tiny apq0): sqrtf(inf)=inf -> rcp(inf)=0 -> t=+-0 safely;
// apq0==0 (tau=NaN) handled by the explicit select.
__device__ __forceinline__ void jrot(float& app, float& aqq, float& apq,
                                     float& arp, float& arq,
                                     float& vap, float& vaq,
                                     float& vbp, float& vbq,
                                     float& vcp, float& vcq) {
  const float apq0 = apq;
  const float tau = (aqq - app) * (0.5f * __builtin_amdgcn_rcpf(apq0));
  float t = copysignf(
      __builtin_amdgcn_rcpf(fabsf(tau) + sqrtf(fmaf(tau, tau, 1.0f))), tau);
  if (apq0 == 0.0f) t = 0.0f;
  const float c = __builtin_amdgcn_rsqf(fmaf(t, t, 1.0f));
  const float s = t * c;
  const float d = t * apq0;
  app -= d; aqq += d; apq = 0.0f;
  float x, y;
  x = arp; y = arq; arp = fmaf(c, x, -(s * y)); arq = fmaf(s, x, c * y);
  x = vap; y = vaq; vap = fmaf(c, x, -(s * y)); vaq = fmaf(s, x, c * y);
  x = vbp; y = vbq; vbp = fmaf(c, x, -(s * y)); vbq = fmaf(s, x, c * y);
  x = vcp; y = vcq; vcp = fmaf(c, x, -(s * y)); vcq = fmaf(s, x, c * y);
}

// Round-6 structure UNCHANGED (A/B isolates the compute diet): 4 phases of
// 16 elements -> LDS 21KB/block -> launch_bounds(256,4) -> 16 waves/CU.
// Only cross-lane RAW fence kept; nontemporal coalesced stores.
__global__ __launch_bounds__(256, 4) void spd_decoder_kernel(
    const float* __restrict__ vech, const float* __restrict__ W1,
    const float* __restrict__ W2, const float* __restrict__ W3,
    float* __restrict__ out, int B) {
  __shared__ float Tsh[21];                      // W2@W1 (7x3)
  __shared__ float Msh[27];                      // W3@W2@W1 (9x3)
  __shared__ __align__(16) float buf[4][1296];   // per-wave staging (16 elem * 81)

  const int tid = threadIdx.x;

  // ---- per-block precompute of M = W3@W2@W1 ----
  if (tid < 21) {
    const int r = tid / 3, c = tid % 3;
    float acc = 0.f;
#pragma unroll
    for (int j = 0; j < 5; ++j) acc += W2[r * 5 + j] * W1[j * 3 + c];
    Tsh[tid] = acc;
  }
  __syncthreads();
  if (tid < 27) {
    const int r = tid / 3, c = tid % 3;
    float acc = 0.f;
#pragma unroll
    for (int j = 0; j < 7; ++j) acc += W3[r * 7 + j] * Tsh[j * 3 + c];
    Msh[tid] = acc;
  }
  __syncthreads();

  // ---- load vech, build symmetric 3x3 ----
  const int e = blockIdx.x * 256 + tid;     // B is a multiple of 256
  const float2* vp = reinterpret_cast<const float2*>(vech + (size_t)e * 6);
  const float2 p0 = vp[0], p1 = vp[1], p2 = vp[2];
  float a00 = p0.x, a01 = p0.y, a02 = p1.x, a11 = p1.y, a12 = p2.x, a22 = p2.y;

  // ---- 3x3 Jacobi, 4 sweeps (12 rotations; quadratic convergence --
  // validated in round 7: absmax identical to 5 sweeps), V accumulated ----
  float v00 = 1.f, v01 = 0.f, v02 = 0.f;
  float v10 = 0.f, v11 = 1.f, v12 = 0.f;
  float v20 = 0.f, v21 = 0.f, v22 = 1.f;
#pragma unroll
  for (int sweep = 0; sweep < 4; ++sweep) {
    jrot(a00, a11, a01, a02, a12, v00, v01, v10, v11, v20, v21);  // (0,1)
    jrot(a00, a22, a02, a01, a12, v00, v02, v10, v12, v20, v22);  // (0,2)
    jrot(a11, a22, a12, a01, a02, v01, v02, v11, v12, v21, v22);  // (1,2)
  }

  const float e0 = exp2f(a00 * LOG2E) - EPSV;
  const float e1 = exp2f(a11 * LOG2E) - EPSV;
  const float e2 = exp2f(a22 * LOG2E) - EPSV;

  // ---- g_k = M v_k; values generated on the fly in the store phases ----
  float g0[9], g1[9], g2[9];
#pragma unroll
  for (int i = 0; i < 9; ++i) {
    const float m0 = Msh[i * 3 + 0], m1 = Msh[i * 3 + 1], m2 = Msh[i * 3 + 2];
    g0[i] = fmaf(m0, v00, fmaf(m1, v10, m2 * v20));
    g1[i] = fmaf(m0, v01, fmaf(m1, v11, m2 * v21));
    g2[i] = fmaf(m0, v02, fmaf(m1, v12, m2 * v22));
  }

  const int w = tid >> 6, l = tid & 63;
  float* wbuf = &buf[w][0];
  const size_t base = (size_t)(blockIdx.x * 256 + w * 64) * 81;

#pragma unroll
  for (int h = 0; h < 4; ++h) {
    if ((l >> 4) == h) {                 // quarter-wave writer group
      const int ll = l & 15;
      float* dst = wbuf + ll * 81;       // word stride 81: conflict-free
#pragma unroll
      for (int i = 0; i < 9; ++i) {
        const float t0 = e0 * g0[i], t1 = e1 * g1[i], t2 = e2 * g2[i];
#pragma unroll
        for (int j = 0; j < 9; ++j) {
          float val = fmaf(t0, g0[j], fmaf(t1, g1[j], t2 * g2[j]));
          if (i == j) val += EPSV;       // compile-time branch after unroll
          dst[i * 9 + j] = val;
        }
      }
    }
    // cross-lane RAW: writes of this phase land before any lane reads them.
    asm volatile("s_waitcnt lgkmcnt(0)" ::: "memory");

    // 1296 contiguous floats = 324 float4, nontemporal (write-once stream)
    const size_t sb = base + (size_t)h * 1296;
    const v4f* rbuf = reinterpret_cast<const v4f*>(wbuf);
    v4f* outv = reinterpret_cast<v4f*>(out + sb);
#pragma unroll
    for (int it = 0; it < 5; ++it)
      __builtin_nontemporal_store(rbuf[it * 64 + l], outv + it * 64 + l);
    if (l < 4) __builtin_nontemporal_store(rbuf[320 + l], outv + 320 + l);
  }
}

extern "C" void kernel_launch(void* const* d_in, const int* in_sizes, int n_in,
                              void* d_out, int out_size, void* d_ws, size_t ws_size,
                              hipStream_t stream) {
  const float* vech = (const float*)d_in[0];
  const float* W1 = (const float*)d_in[1];
  const float* W2 = (const float*)d_in[2];
  const float* W3 = (const float*)d_in[3];
  float* out = (float*)d_out;
  const int B = in_sizes[0] / 6;  // 262144
  dim3 grid(B / 256), block(256);
  hipLaunchKernelGGL(spd_decoder_kernel, grid, block, 0, stream,
                     vech, W1, W2, W3, out, B);
}